// Round 11
// baseline (140.379 us; speedup 1.0000x reference)
//
#include <hip/hip_runtime.h>
#include <math.h>

#define BS 4
#define SEG 512
#define NV 8
#define DIN 256
#define NH 8
#define DQ 32
#define NP (NH * NV * BS)  // 256 attention problems
// flat m = ((b*SEG+s)*NV+v); attention problem p = (h*NV+v)*BS+b (z batch order)

typedef __attribute__((ext_vector_type(8))) short bf16x8;
typedef __attribute__((ext_vector_type(4))) float f32x4;

static __device__ __forceinline__ unsigned short f2bf(float f) {
  unsigned int x = __builtin_bit_cast(unsigned int, f);
  return (unsigned short)((x + 0x7fffu + ((x >> 16) & 1u)) >> 16);  // RNE
}

static __device__ __forceinline__ bf16x8 pk8(const float4 a, const float4 b) {
  bf16x8 t;
  t[0] = (short)f2bf(a.x); t[1] = (short)f2bf(a.y);
  t[2] = (short)f2bf(a.z); t[3] = (short)f2bf(a.w);
  t[4] = (short)f2bf(b.x); t[5] = (short)f2bf(b.y);
  t[6] = (short)f2bf(b.z); t[7] = (short)f2bf(b.w);
  return t;
}

// async global->LDS, 16B per lane; LDS dest = wave-uniform base + lane*16
static __device__ __forceinline__ void gl16(const void* g, void* l) {
  __builtin_amdgcn_global_load_lds(
      (const __attribute__((address_space(1))) void*)g,
      (__attribute__((address_space(3))) void*)(
          (unsigned int)(unsigned long long)(uintptr_t)l),
      16, 0, 0);
}

// ---------------------------------------------------------------------------
// K1: FUSED  [blocks 0..1023]  z fp32->bf16 convert   (memory-bound)
//            [blocks 1024..1535] q = (x@w_q^T+b_q)*C2 (MFMA; reads fp32 direct)
// Independent work -> one dispatch: saves a launch boundary and overlaps the
// BW-bound cvt with the compute-bound GEMM. C2 = log2(e)/sqrt(32).
// ---------------------------------------------------------------------------
__global__ __launch_bounds__(256) void k_pre(
    const float* __restrict__ z, const float* __restrict__ x,
    const float* __restrict__ wq, const float* __restrict__ bq,
    unsigned short* __restrict__ zb, unsigned short* __restrict__ q_bf)
{
  __shared__ unsigned short As[2][64 * 64];    // 8KB x2, swizzled (qproj path)
  __shared__ unsigned short Bs[2][128 * 64];   // 16KB x2, swizzled
  const int tid = threadIdx.x;

  if (blockIdx.x < 1024) {
    // ---- cvt_z path ----
    const size_t i0 = (size_t)(blockIdx.x * 256 + tid) * 16;
    const float4 a = *(const float4*)(z + i0);
    const float4 b = *(const float4*)(z + i0 + 4);
    const float4 c = *(const float4*)(z + i0 + 8);
    const float4 d = *(const float4*)(z + i0 + 12);
    *(bf16x8*)(zb + i0) = pk8(a, b);
    *(bf16x8*)(zb + i0 + 8) = pk8(c, d);
    return;
  }

  // ---- qproj path ----
  const int bid = blockIdx.x - 1024;
  const int wid = tid >> 6, lane = tid & 63;
  const int c = lane & 15, g = lane >> 4;
  const int m0 = (bid >> 1) * 64;
  const int e0 = (bid & 1) * 128;
  const int wm = wid >> 1, wn = wid & 1;
  // staging coords
  const int ar = tid >> 2, ak = (tid & 3) * 16;   // A: 64 rows x 64 k
  const int br = tid >> 1, bk = (tid & 1) * 32;   // B: 128 rows x 64 k
  const int aswz = (ar & 7) << 3, bswz = (br & 7) << 3;
  const int fswz = (c & 7) << 3;                  // frag-read swizzle

  float4 av[4], bv[8];
#define QP_LOAD(kt)                                                              \
  {                                                                              \
    _Pragma("unroll") for (int j = 0; j < 4; ++j)                                \
        av[j] = *(const float4*)&x[(size_t)(m0 + ar) * DIN + (kt)*64 + ak + j*4];\
    _Pragma("unroll") for (int j = 0; j < 8; ++j)                                \
        bv[j] = *(const float4*)&wq[(size_t)(e0 + br) * DIN + (kt)*64 + bk + j*4];\
  }
#define QP_WRITE(buf)                                                            \
  {                                                                              \
    _Pragma("unroll") for (int h = 0; h < 2; ++h)                                \
        *(bf16x8*)&As[buf][ar * 64 + ((ak + h * 8) ^ aswz)] =                    \
            pk8(av[2 * h], av[2 * h + 1]);                                       \
    _Pragma("unroll") for (int h = 0; h < 4; ++h)                                \
        *(bf16x8*)&Bs[buf][br * 64 + ((bk + h * 8) ^ bswz)] =                    \
            pk8(bv[2 * h], bv[2 * h + 1]);                                       \
  }

  f32x4 acc[2][4];
#pragma unroll
  for (int mi = 0; mi < 2; ++mi)
#pragma unroll
    for (int nj = 0; nj < 4; ++nj) acc[mi][nj] = (f32x4){0.f, 0.f, 0.f, 0.f};

  QP_LOAD(0);
  QP_WRITE(0);
  __syncthreads();
  for (int kt = 0; kt < 4; ++kt) {
    const int buf = kt & 1;
    if (kt < 3) QP_LOAD(kt + 1);  // issue early; consumed by QP_WRITE below
    bf16x8 af[2][2], bfr[2][4];
#pragma unroll
    for (int kk = 0; kk < 2; ++kk) {
#pragma unroll
      for (int mi = 0; mi < 2; ++mi)
        af[kk][mi] = *(const bf16x8*)
            &As[buf][(wm * 32 + mi * 16 + c) * 64 + ((kk * 32 + g * 8) ^ fswz)];
#pragma unroll
      for (int nj = 0; nj < 4; ++nj)
        bfr[kk][nj] = *(const bf16x8*)
            &Bs[buf][(wn * 64 + nj * 16 + c) * 64 + ((kk * 32 + g * 8) ^ fswz)];
    }
#pragma unroll
    for (int kk = 0; kk < 2; ++kk)
#pragma unroll
      for (int mi = 0; mi < 2; ++mi)
#pragma unroll
        for (int nj = 0; nj < 4; ++nj)
          acc[mi][nj] = __builtin_amdgcn_mfma_f32_16x16x32_bf16(af[kk][mi], bfr[kk][nj],
                                                                acc[mi][nj], 0, 0, 0);
    if (kt < 3) QP_WRITE(buf ^ 1);  // disjoint buffer: safe while others read buf
    __syncthreads();
  }
#undef QP_LOAD
#undef QP_WRITE

  const float C2 = 0.2550348f;  // log2(e)/sqrt(32)
#pragma unroll
  for (int nj = 0; nj < 4; ++nj) {
    const int e = e0 + wn * 64 + nj * 16 + c;
    const float bqe = bq[e];
    const int h = e >> 5, dq = e & 31;
#pragma unroll
    for (int mi = 0; mi < 2; ++mi)
#pragma unroll
      for (int r = 0; r < 4; ++r) {
        const int m = m0 + wm * 32 + mi * 16 + g * 4 + r;
        const int b = m >> 12, s = (m >> 3) & 511, v = m & 7;
        const int p = (h * NV + v) * BS + b;
        q_bf[(size_t)(p * SEG + s) * DQ + dq] = f2bf((acc[mi][nj][r] + bqe) * C2);
      }
  }
}

// ---------------------------------------------------------------------------
// K2: MFMA flash attention (unchanged — passed R6/R10).
// ---------------------------------------------------------------------------
__global__ __launch_bounds__(512, 4) void k_attn5(
    const unsigned short* __restrict__ qb, const unsigned short* __restrict__ zb,
    unsigned short* __restrict__ att)
{
  __shared__ unsigned short zT[32 * 512];     // 32 KB  [d][t ^ ((d&7)<<3)]
  __shared__ unsigned short Pl[8 * 32 * 64];  // 32 KB  per-wave [q][t ^ ((q&7)<<3)]
  __shared__ float linv[8 * 32];              // 1 KB
  const int tid = threadIdx.x;
  const int p = blockIdx.x >> 1;
  const int wid = tid >> 6;
  const int lane = tid & 63;
  const int c = lane & 15;
  const int g = lane >> 4;
  const int q0 = (blockIdx.x & 1) * 256 + wid * 32;
  const size_t zoff = (size_t)p * (SEG * DQ);

  bf16x8 qf[2];
#pragma unroll
  for (int qi = 0; qi < 2; ++qi)
    qf[qi] = *(const bf16x8*)(qb + zoff + (size_t)(q0 + qi * 16 + c) * DQ + g * 8);

#pragma unroll
  for (int r = 0; r < 4; ++r) {
    const int t = (tid & 127) + r * 128;
    const int d0 = (tid >> 7) * 8;
    const bf16x8 v = *(const bf16x8*)(zb + zoff + (size_t)t * DQ + d0);
#pragma unroll
    for (int j = 0; j < 8; ++j) {
      const int d = d0 + j;
      zT[d * 512 + (t ^ ((d & 7) << 3))] = (unsigned short)v[j];
    }
  }

  f32x4 oacc[2][2];
#pragma unroll
  for (int qi = 0; qi < 2; ++qi)
#pragma unroll
    for (int dj = 0; dj < 2; ++dj)
      oacc[qi][dj] = (f32x4){0.f, 0.f, 0.f, 0.f};
  float lsum[2] = {0.f, 0.f};

  bf16x8 az[4];
#pragma unroll
  for (int tj = 0; tj < 4; ++tj)
    az[tj] = *(const bf16x8*)(zb + zoff + (size_t)(tj * 16 + c) * DQ + g * 8);

  __syncthreads();

  const unsigned pbase = wid * 2048;
  const int swz = (c & 7) << 3;

  for (int t0 = 0; t0 < SEG; t0 += 64) {
    f32x4 sv[2][4];
#pragma unroll
    for (int qi = 0; qi < 2; ++qi)
#pragma unroll
      for (int tj = 0; tj < 4; ++tj) {
        const f32x4 zero = {0.f, 0.f, 0.f, 0.f};
        sv[qi][tj] = __builtin_amdgcn_mfma_f32_16x16x32_bf16(az[tj], qf[qi], zero, 0, 0, 0);
      }
    const int tn = (t0 + 64 < SEG) ? (t0 + 64) : 0;
#pragma unroll
    for (int tj = 0; tj < 4; ++tj)
      az[tj] = *(const bf16x8*)(zb + zoff + (size_t)(tn + tj * 16 + c) * DQ + g * 8);

#pragma unroll
    for (int qi = 0; qi < 2; ++qi) {
#pragma unroll
      for (int tj = 0; tj < 4; ++tj) {
        const float e0 = __builtin_amdgcn_exp2f(sv[qi][tj][0]);
        const float e1 = __builtin_amdgcn_exp2f(sv[qi][tj][1]);
        const float e2 = __builtin_amdgcn_exp2f(sv[qi][tj][2]);
        const float e3 = __builtin_amdgcn_exp2f(sv[qi][tj][3]);
        lsum[qi] += (e0 + e1) + (e2 + e3);
        const unsigned lo = __builtin_amdgcn_perm(
            __builtin_bit_cast(unsigned, e1), __builtin_bit_cast(unsigned, e0), 0x07060302u);
        const unsigned hi = __builtin_amdgcn_perm(
            __builtin_bit_cast(unsigned, e3), __builtin_bit_cast(unsigned, e2), 0x07060302u);
        uint2 u = {lo, hi};
        *(uint2*)&Pl[pbase + (qi * 16 + c) * 64 + ((tj * 16 + g * 4) ^ swz)] = u;
      }
    }
#pragma unroll
    for (int ks = 0; ks < 2; ++ks) {
      bf16x8 zf[2];
#pragma unroll
      for (int dj = 0; dj < 2; ++dj) {
        const int d = dj * 16 + c;
        zf[dj] = *(const bf16x8*)&zT[d * 512 + ((t0 + ks * 32 + g * 8) ^ ((d & 7) << 3))];
      }
#pragma unroll
      for (int qi = 0; qi < 2; ++qi) {
        const bf16x8 pa =
            *(const bf16x8*)&Pl[pbase + (qi * 16 + c) * 64 + ((ks * 32 + g * 8) ^ swz)];
        oacc[qi][0] = __builtin_amdgcn_mfma_f32_16x16x32_bf16(pa, zf[0], oacc[qi][0], 0, 0, 0);
        oacc[qi][1] = __builtin_amdgcn_mfma_f32_16x16x32_bf16(pa, zf[1], oacc[qi][1], 0, 0, 0);
      }
    }
  }

#pragma unroll
  for (int qi = 0; qi < 2; ++qi) {
    lsum[qi] += __shfl_xor(lsum[qi], 16);
    lsum[qi] += __shfl_xor(lsum[qi], 32);
  }
  if (g == 0) {
#pragma unroll
    for (int qi = 0; qi < 2; ++qi) linv[wid * 32 + qi * 16 + c] = 1.f / lsum[qi];
  }
  const int b = p & 3, v = (p >> 2) & 7, h = p >> 5;
#pragma unroll
  for (int qi = 0; qi < 2; ++qi) {
    const f32x4 iv = *(const f32x4*)&linv[wid * 32 + qi * 16 + g * 4];
#pragma unroll
    for (int dj = 0; dj < 2; ++dj)
#pragma unroll
      for (int r = 0; r < 4; ++r) {
        const int s = q0 + qi * 16 + g * 4 + r;
        att[((size_t)((b * SEG + s) * NV + v)) * DIN + h * DQ + dj * 16 + c] =
            f2bf(oacc[qi][dj][r] * iv[r]);
      }
  }
}

// ---------------------------------------------------------------------------
// K3: out = LN( att @ fc_w^T + fc_b + x ). A=att2 bf16 via global_load_lds
// (linear LDS); B=fcw fp32 reg-staged+converted, XOR-swizzled (T2).
// BM=64, BN=256, BK=64, 8 waves. fp32 residual + LN epilogue.
// ---------------------------------------------------------------------------
__global__ __launch_bounds__(512) void k_fcln3(
    const unsigned short* __restrict__ ab, const float* __restrict__ fcw,
    const float* __restrict__ x, const float* __restrict__ fcb,
    const float* __restrict__ gamma, const float* __restrict__ beta,
    float* __restrict__ out)
{
  __shared__ __align__(16) unsigned char smem[81920];  // GEMM bufs / LN overlay
  unsigned short* As = (unsigned short*)smem;            // [2][64*64]   16KB
  unsigned short* Bs = (unsigned short*)(smem + 16384);  // [2][256*64]  64KB
  float* red_s = (float*)smem;                           // [64][68] overlay
  float* red_q = (float*)(smem + 17408);                 // [64][68]
  float* mu_l = (float*)(smem + 34816);                  // [64]
  float* rs_l = (float*)(smem + 35072);                  // [64]

  const int tid = threadIdx.x;
  const int wid = tid >> 6, lane = tid & 63;
  const int c = lane & 15, g = lane >> 4;
  const int m0 = blockIdx.x * 64;
  const int wm = wid >> 2, wn = wid & 3;
  const int br = tid >> 1, bk = (tid & 1) * 32;   // B staging: 256 rows x 64 k
  const int bswz = (br & 7) << 3;
  const int fswz = (c & 7) << 3;

  float4 bv[8];
#define FC_GLA(buf, kt)                                                         \
  {                                                                             \
    const int idx = wid * 64 + lane;                                            \
    gl16(ab + (size_t)(m0 + (idx >> 3)) * DIN + (kt)*64 + (idx & 7) * 8,        \
         &As[(buf)*4096 + wid * 512]);                                          \
  }
#define FC_LOADB(kt)                                                            \
  {                                                                             \
    _Pragma("unroll") for (int j = 0; j < 8; ++j)                               \
        bv[j] = *(const float4*)&fcw[(size_t)br * DIN + (kt)*64 + bk + j * 4];  \
  }
#define FC_WRITEB(buf)                                                          \
  {                                                                             \
    _Pragma("unroll") for (int h = 0; h < 4; ++h)                               \
        *(bf16x8*)&Bs[(buf)*16384 + br * 64 + ((bk + h * 8) ^ bswz)] =          \
            pk8(bv[2 * h], bv[2 * h + 1]);                                      \
  }

  f32x4 acc[2][4];
#pragma unroll
  for (int mi = 0; mi < 2; ++mi)
#pragma unroll
    for (int nj = 0; nj < 4; ++nj) acc[mi][nj] = (f32x4){0.f, 0.f, 0.f, 0.f};

  FC_GLA(0, 0);
  FC_LOADB(0);
  FC_WRITEB(0);
  __syncthreads();  // also drains gl16 (compiler vmcnt before barrier)
  for (int kt = 0; kt < 4; ++kt) {
    const int buf = kt & 1;
    if (kt < 3) {
      FC_GLA(buf ^ 1, kt + 1);
      FC_LOADB(kt + 1);
    }
    bf16x8 af[2][2], bfr[2][4];
#pragma unroll
    for (int kk = 0; kk < 2; ++kk) {
#pragma unroll
      for (int mi = 0; mi < 2; ++mi)
        af[kk][mi] = *(const bf16x8*)
            &As[buf * 4096 + (wm * 32 + mi * 16 + c) * 64 + kk * 32 + g * 8];
#pragma unroll
      for (int nj = 0; nj < 4; ++nj)
        bfr[kk][nj] = *(const bf16x8*)
            &Bs[buf * 16384 + (wn * 64 + nj * 16 + c) * 64 + ((kk * 32 + g * 8) ^ fswz)];
    }
#pragma unroll
    for (int kk = 0; kk < 2; ++kk)
#pragma unroll
      for (int mi = 0; mi < 2; ++mi)
#pragma unroll
        for (int nj = 0; nj < 4; ++nj)
          acc[mi][nj] = __builtin_amdgcn_mfma_f32_16x16x32_bf16(af[kk][mi], bfr[kk][nj],
                                                                acc[mi][nj], 0, 0, 0);
    if (kt < 3) FC_WRITEB(buf ^ 1);
    __syncthreads();
  }
#undef FC_GLA
#undef FC_LOADB
#undef FC_WRITEB

  // bias + residual (fp32) + per-row partial sums
#pragma unroll
  for (int mi = 0; mi < 2; ++mi)
#pragma unroll
    for (int r = 0; r < 4; ++r) {
      const int row = wm * 32 + mi * 16 + g * 4 + r;
      const int m = m0 + row;
      float s_ = 0.f, q_ = 0.f;
#pragma unroll
      for (int nj = 0; nj < 4; ++nj) {
        const int d = wn * 64 + nj * 16 + c;
        const float v = acc[mi][nj][r] + fcb[d] + x[(size_t)m * DIN + d];
        acc[mi][nj][r] = v;
        s_ += v;
        q_ += v * v;
      }
      red_s[row * 68 + wn * 16 + c] = s_;
      red_q[row * 68 + wn * 16 + c] = q_;
    }
  __syncthreads();
  if (tid < 64) {
    float ss = 0.f, qs = 0.f;
#pragma unroll 8
    for (int j = 0; j < 64; ++j) { ss += red_s[tid * 68 + j]; qs += red_q[tid * 68 + j]; }
    const float mu = ss * (1.f / DIN);
    const float var = qs * (1.f / DIN) - mu * mu;
    mu_l[tid] = mu;
    rs_l[tid] = rsqrtf(var + 1e-5f);
  }
  __syncthreads();
#pragma unroll
  for (int mi = 0; mi < 2; ++mi)
#pragma unroll
    for (int r = 0; r < 4; ++r) {
      const int row = wm * 32 + mi * 16 + g * 4 + r;
      const int m = m0 + row;
      const float mu = mu_l[row], rs = rs_l[row];
#pragma unroll
      for (int nj = 0; nj < 4; ++nj) {
        const int d = wn * 64 + nj * 16 + c;
        out[(size_t)m * DIN + d] = (acc[mi][nj][r] - mu) * rs * gamma[d] + beta[d];
      }
    }
}

// ---------------------------------------------------------------------------
extern "C" void kernel_launch(void* const* d_in, const int* in_sizes, int n_in,
                              void* d_out, int out_size, void* d_ws, size_t ws_size,
                              hipStream_t stream) {
  const float* x   = (const float*)d_in[0];
  const float* z   = (const float*)d_in[1];
  const float* wq  = (const float*)d_in[2];
  const float* bq  = (const float*)d_in[3];
  const float* fcw = (const float*)d_in[4];
  const float* fcb = (const float*)d_in[5];
  const float* g   = (const float*)d_in[6];
  const float* be  = (const float*)d_in[7];
  float* outp = (float*)d_out;

  unsigned short* q_bf = (unsigned short*)d_ws;            // 8 MB
  unsigned short* z_bf = q_bf + (size_t)NP * SEG * DQ;     // 8 MB
  unsigned short* att2 = z_bf + (size_t)NP * SEG * DQ;     // 8 MB

  k_pre  <<<1536, 256, 0, stream>>>(z, x, wq, bq, z_bf, q_bf);
  k_attn5<<<NP * 2, 512, 0, stream>>>(q_bf, z_bf, att2);
  k_fcln3<<<256, 512, 0, stream>>>(att2, fcw, x, fcb, g, be, outp);
}

// Round 12
// 130.281 us; speedup vs baseline: 1.0775x; 1.0775x over previous
//
#include <hip/hip_runtime.h>
#include <math.h>

#define BS 4
#define SEG 512
#define NV 8
#define DIN 256
#define NH 8
#define DQ 32
#define NP (NH * NV * BS)  // 256 attention problems
// flat m = ((b*SEG+s)*NV+v); attention problem p = (h*NV+v)*BS+b (z batch order)

typedef __attribute__((ext_vector_type(8))) short bf16x8;
typedef __attribute__((ext_vector_type(4))) float f32x4;

static __device__ __forceinline__ unsigned short f2bf(float f) {
  unsigned int x = __builtin_bit_cast(unsigned int, f);
  return (unsigned short)((x + 0x7fffu + ((x >> 16) & 1u)) >> 16);  // RNE
}

// async global->LDS, 16B per lane; LDS dest = wave-uniform base + lane*16
static __device__ __forceinline__ void gl16(const void* g, void* l) {
  __builtin_amdgcn_global_load_lds(
      (const __attribute__((address_space(1))) void*)g,
      (__attribute__((address_space(3))) void*)(
          (unsigned int)(unsigned long long)(uintptr_t)l),
      16, 0, 0);
}

// ---------------------------------------------------------------------------
// K0: convert z, x, w_q, fc_w  fp32 -> bf16 (one pass)
// ---------------------------------------------------------------------------
#define CVT_NZ 262144   // z chunks of 16
#define CVT_NX 262144   // x chunks
#define CVT_NW 4096     // wq chunks
#define CVT_NF 4096     // fcw chunks
__global__ __launch_bounds__(256) void k_cvt(
    const float* __restrict__ z, const float* __restrict__ x,
    const float* __restrict__ wq, const float* __restrict__ fcw,
    unsigned short* __restrict__ zb, unsigned short* __restrict__ xb,
    unsigned short* __restrict__ wqb, unsigned short* __restrict__ fwb)
{
  const int gid = blockIdx.x * 256 + threadIdx.x;
  const float* src;
  unsigned short* dst;
  int off;
  if (gid < CVT_NZ) { src = z; dst = zb; off = gid; }
  else if (gid < CVT_NZ + CVT_NX) { src = x; dst = xb; off = gid - CVT_NZ; }
  else if (gid < CVT_NZ + CVT_NX + CVT_NW) { src = wq; dst = wqb; off = gid - CVT_NZ - CVT_NX; }
  else { src = fcw; dst = fwb; off = gid - CVT_NZ - CVT_NX - CVT_NW; }
  const size_t i0 = (size_t)off * 16;
  const float4 a = *(const float4*)(src + i0);
  const float4 b = *(const float4*)(src + i0 + 4);
  const float4 c = *(const float4*)(src + i0 + 8);
  const float4 d = *(const float4*)(src + i0 + 12);
  ushort4 u0 = {f2bf(a.x), f2bf(a.y), f2bf(a.z), f2bf(a.w)};
  ushort4 u1 = {f2bf(b.x), f2bf(b.y), f2bf(b.z), f2bf(b.w)};
  ushort4 u2 = {f2bf(c.x), f2bf(c.y), f2bf(c.z), f2bf(c.w)};
  ushort4 u3 = {f2bf(d.x), f2bf(d.y), f2bf(d.z), f2bf(d.w)};
  *(ushort4*)(dst + i0) = u0;
  *(ushort4*)(dst + i0 + 4) = u1;
  *(ushort4*)(dst + i0 + 8) = u2;
  *(ushort4*)(dst + i0 + 12) = u3;
}

// ---------------------------------------------------------------------------
// K1: q = (x @ w_q^T + b_q) * C2   MFMA bf16. BM=64, BN=128, BK=64, 4 waves.
// C2 = log2(e)/sqrt(32): attn then uses bare v_exp_f32 (2^x) == exp(s).
// ---------------------------------------------------------------------------
__global__ __launch_bounds__(256) void k_qproj2(
    const unsigned short* __restrict__ xb, const unsigned short* __restrict__ wqb,
    const float* __restrict__ bq, unsigned short* __restrict__ q_bf)
{
  __shared__ unsigned short As[2][64 * 64];    // 8KB x2
  __shared__ unsigned short Bsh[2][128 * 64];  // 16KB x2
  const int tid = threadIdx.x;
  const int wid = tid >> 6, lane = tid & 63;
  const int c = lane & 15, g = lane >> 4;
  const int m0 = (blockIdx.x >> 1) * 64;
  const int e0 = (blockIdx.x & 1) * 128;
  const int wm = wid >> 1, wn = wid & 1;

  f32x4 acc[2][4];
#pragma unroll
  for (int mi = 0; mi < 2; ++mi)
#pragma unroll
    for (int nj = 0; nj < 4; ++nj) acc[mi][nj] = (f32x4){0.f, 0.f, 0.f, 0.f};

#define QP_STAGE(buf, kt)                                                        \
  {                                                                              \
    _Pragma("unroll") for (int i = 0; i < 2; ++i) {                              \
      const int idx = (wid * 2 + i) * 64 + lane;                                 \
      gl16(xb + (size_t)(m0 + (idx >> 3)) * DIN + (kt)*64 + (idx & 7) * 8,       \
           &As[buf][(wid * 2 + i) * 512]);                                       \
    }                                                                            \
    _Pragma("unroll") for (int i = 0; i < 4; ++i) {                              \
      const int idx = (wid * 4 + i) * 64 + lane;                                 \
      gl16(wqb + (size_t)(e0 + (idx >> 3)) * DIN + (kt)*64 + (idx & 7) * 8,      \
           &Bsh[buf][(wid * 4 + i) * 512]);                                      \
    }                                                                            \
  }

  QP_STAGE(0, 0);
  __syncthreads();
  for (int kt = 0; kt < 4; ++kt) {
    const int buf = kt & 1;
    if (kt < 3) QP_STAGE(buf ^ 1, kt + 1);
    bf16x8 af[2][2], bfr[2][4];
#pragma unroll
    for (int kk = 0; kk < 2; ++kk) {
#pragma unroll
      for (int mi = 0; mi < 2; ++mi)
        af[kk][mi] = *(const bf16x8*)&As[buf][(wm * 32 + mi * 16 + c) * 64 + kk * 32 + g * 8];
#pragma unroll
      for (int nj = 0; nj < 4; ++nj)
        bfr[kk][nj] = *(const bf16x8*)&Bsh[buf][(wn * 64 + nj * 16 + c) * 64 + kk * 32 + g * 8];
    }
#pragma unroll
    for (int kk = 0; kk < 2; ++kk)
#pragma unroll
      for (int mi = 0; mi < 2; ++mi)
#pragma unroll
        for (int nj = 0; nj < 4; ++nj)
          acc[mi][nj] = __builtin_amdgcn_mfma_f32_16x16x32_bf16(af[kk][mi], bfr[kk][nj],
                                                                acc[mi][nj], 0, 0, 0);
    __syncthreads();
  }
#undef QP_STAGE

  const float C2 = 0.2550348f;  // log2(e)/sqrt(32)
#pragma unroll
  for (int nj = 0; nj < 4; ++nj) {
    const int e = e0 + wn * 64 + nj * 16 + c;
    const float bqe = bq[e];
    const int h = e >> 5, dq = e & 31;
#pragma unroll
    for (int mi = 0; mi < 2; ++mi)
#pragma unroll
      for (int r = 0; r < 4; ++r) {
        const int m = m0 + wm * 32 + mi * 16 + g * 4 + r;
        const int b = m >> 12, s = (m >> 3) & 511, v = m & 7;
        const int p = (h * NV + v) * BS + b;
        q_bf[(size_t)(p * SEG + s) * DQ + dq] = f2bf((acc[mi][nj][r] + bqe) * C2);
      }
  }
}

// ---------------------------------------------------------------------------
// K2: MFMA flash attention. 2 blocks per p (q-halves), 8 waves/block,
// 32 q-rows per wave, wave-private P. Softmax VALU-trimmed via builtins only:
// __builtin_amdgcn_exp2f (v_exp_f32, log2e pre-folded into q) and
// __builtin_amdgcn_perm (1-instr bf16 truncation pack of 2 values).
// NO inline asm: TRANS-op hazards must stay compiler-managed (round-5 NaN).
// ---------------------------------------------------------------------------
__global__ __launch_bounds__(512, 4) void k_attn5(
    const unsigned short* __restrict__ qb, const unsigned short* __restrict__ zb,
    unsigned short* __restrict__ att)
{
  __shared__ unsigned short zT[32 * 512];     // 32 KB  [d][t ^ ((d&7)<<3)]
  __shared__ unsigned short Pl[8 * 32 * 64];  // 32 KB  per-wave [q][t ^ ((q&7)<<3)]
  __shared__ float linv[8 * 32];              // 1 KB
  const int tid = threadIdx.x;
  const int p = blockIdx.x >> 1;
  const int wid = tid >> 6;
  const int lane = tid & 63;
  const int c = lane & 15;
  const int g = lane >> 4;
  const int q0 = (blockIdx.x & 1) * 256 + wid * 32;
  const size_t zoff = (size_t)p * (SEG * DQ);

  bf16x8 qf[2];
#pragma unroll
  for (int qi = 0; qi < 2; ++qi)
    qf[qi] = *(const bf16x8*)(qb + zoff + (size_t)(q0 + qi * 16 + c) * DQ + g * 8);

#pragma unroll
  for (int r = 0; r < 4; ++r) {
    const int t = (tid & 127) + r * 128;
    const int d0 = (tid >> 7) * 8;
    const bf16x8 v = *(const bf16x8*)(zb + zoff + (size_t)t * DQ + d0);
#pragma unroll
    for (int j = 0; j < 8; ++j) {
      const int d = d0 + j;
      zT[d * 512 + (t ^ ((d & 7) << 3))] = (unsigned short)v[j];
    }
  }

  f32x4 oacc[2][2];
#pragma unroll
  for (int qi = 0; qi < 2; ++qi)
#pragma unroll
    for (int dj = 0; dj < 2; ++dj)
      oacc[qi][dj] = (f32x4){0.f, 0.f, 0.f, 0.f};
  float lsum[2] = {0.f, 0.f};

  bf16x8 az[4];
#pragma unroll
  for (int tj = 0; tj < 4; ++tj)
    az[tj] = *(const bf16x8*)(zb + zoff + (size_t)(tj * 16 + c) * DQ + g * 8);

  __syncthreads();

  const unsigned pbase = wid * 2048;
  const int swz = (c & 7) << 3;

  for (int t0 = 0; t0 < SEG; t0 += 64) {
    f32x4 sv[2][4];
#pragma unroll
    for (int qi = 0; qi < 2; ++qi)
#pragma unroll
      for (int tj = 0; tj < 4; ++tj) {
        const f32x4 zero = {0.f, 0.f, 0.f, 0.f};
        sv[qi][tj] = __builtin_amdgcn_mfma_f32_16x16x32_bf16(az[tj], qf[qi], zero, 0, 0, 0);
      }
    const int tn = (t0 + 64 < SEG) ? (t0 + 64) : 0;
#pragma unroll
    for (int tj = 0; tj < 4; ++tj)
      az[tj] = *(const bf16x8*)(zb + zoff + (size_t)(tn + tj * 16 + c) * DQ + g * 8);

#pragma unroll
    for (int qi = 0; qi < 2; ++qi) {
#pragma unroll
      for (int tj = 0; tj < 4; ++tj) {
        const float e0 = __builtin_amdgcn_exp2f(sv[qi][tj][0]);
        const float e1 = __builtin_amdgcn_exp2f(sv[qi][tj][1]);
        const float e2 = __builtin_amdgcn_exp2f(sv[qi][tj][2]);
        const float e3 = __builtin_amdgcn_exp2f(sv[qi][tj][3]);
        lsum[qi] += (e0 + e1) + (e2 + e3);
        // pack bf16 truncations: D = {hi16(odd), hi16(even)} in one v_perm_b32
        const unsigned lo = __builtin_amdgcn_perm(
            __builtin_bit_cast(unsigned, e1), __builtin_bit_cast(unsigned, e0), 0x07060302u);
        const unsigned hi = __builtin_amdgcn_perm(
            __builtin_bit_cast(unsigned, e3), __builtin_bit_cast(unsigned, e2), 0x07060302u);
        uint2 u = {lo, hi};
        *(uint2*)&Pl[pbase + (qi * 16 + c) * 64 + ((tj * 16 + g * 4) ^ swz)] = u;
      }
    }
#pragma unroll
    for (int ks = 0; ks < 2; ++ks) {
      bf16x8 zf[2];
#pragma unroll
      for (int dj = 0; dj < 2; ++dj) {
        const int d = dj * 16 + c;
        zf[dj] = *(const bf16x8*)&zT[d * 512 + ((t0 + ks * 32 + g * 8) ^ ((d & 7) << 3))];
      }
#pragma unroll
      for (int qi = 0; qi < 2; ++qi) {
        const bf16x8 pa =
            *(const bf16x8*)&Pl[pbase + (qi * 16 + c) * 64 + ((ks * 32 + g * 8) ^ swz)];
        oacc[qi][0] = __builtin_amdgcn_mfma_f32_16x16x32_bf16(pa, zf[0], oacc[qi][0], 0, 0, 0);
        oacc[qi][1] = __builtin_amdgcn_mfma_f32_16x16x32_bf16(pa, zf[1], oacc[qi][1], 0, 0, 0);
      }
    }
  }

#pragma unroll
  for (int qi = 0; qi < 2; ++qi) {
    lsum[qi] += __shfl_xor(lsum[qi], 16);
    lsum[qi] += __shfl_xor(lsum[qi], 32);
  }
  if (g == 0) {
#pragma unroll
    for (int qi = 0; qi < 2; ++qi) linv[wid * 32 + qi * 16 + c] = 1.f / lsum[qi];
  }
  const int b = p & 3, v = (p >> 2) & 7, h = p >> 5;
#pragma unroll
  for (int qi = 0; qi < 2; ++qi) {
    const f32x4 iv = *(const f32x4*)&linv[wid * 32 + qi * 16 + g * 4];
#pragma unroll
    for (int dj = 0; dj < 2; ++dj)
#pragma unroll
      for (int r = 0; r < 4; ++r) {
        const int s = q0 + qi * 16 + g * 4 + r;
        att[((size_t)((b * SEG + s) * NV + v)) * DIN + h * DQ + dj * 16 + c] =
            f2bf(oacc[qi][dj][r] * iv[r]);
      }
  }
}

// ---------------------------------------------------------------------------
// K3: out = LN( att @ fc_w^T + fc_b + x ). MFMA bf16. BM=64, BN=256, BK=64,
// 8 waves (wave 32x64). fp32 residual + LN epilogue via LDS reduction.
// ---------------------------------------------------------------------------
__global__ __launch_bounds__(512) void k_fcln2(
    const unsigned short* __restrict__ ab, const unsigned short* __restrict__ fwb,
    const float* __restrict__ x, const float* __restrict__ fcb,
    const float* __restrict__ gamma, const float* __restrict__ beta,
    float* __restrict__ out)
{
  __shared__ __align__(16) unsigned char smem[81920];  // GEMM bufs / LN overlay
  unsigned short* As = (unsigned short*)smem;            // [2][64*64]   16KB
  unsigned short* Bsh = (unsigned short*)(smem + 16384); // [2][256*64]  64KB
  float* red_s = (float*)smem;                           // [64][68]
  float* red_q = (float*)(smem + 17408);                 // [64][68]
  float* mu_l = (float*)(smem + 34816);                  // [64]
  float* rs_l = (float*)(smem + 35072);                  // [64]

  const int tid = threadIdx.x;
  const int wid = tid >> 6, lane = tid & 63;
  const int c = lane & 15, g = lane >> 4;
  const int m0 = blockIdx.x * 64;
  const int wm = wid >> 2, wn = wid & 3;

  f32x4 acc[2][4];
#pragma unroll
  for (int mi = 0; mi < 2; ++mi)
#pragma unroll
    for (int nj = 0; nj < 4; ++nj) acc[mi][nj] = (f32x4){0.f, 0.f, 0.f, 0.f};

#define FC_STAGE(buf, kt)                                                       \
  {                                                                             \
    {                                                                           \
      const int idx = wid * 64 + lane;                                          \
      gl16(ab + (size_t)(m0 + (idx >> 3)) * DIN + (kt)*64 + (idx & 7) * 8,      \
           &As[(buf)*4096 + wid * 512]);                                        \
    }                                                                           \
    _Pragma("unroll") for (int i = 0; i < 4; ++i) {                             \
      const int idx = (wid * 4 + i) * 64 + lane;                                \
      gl16(fwb + (size_t)(idx >> 3) * DIN + (kt)*64 + (idx & 7) * 8,            \
           &Bsh[(buf)*16384 + (wid * 4 + i) * 512]);                            \
    }                                                                           \
  }

  FC_STAGE(0, 0);
  __syncthreads();
  for (int kt = 0; kt < 4; ++kt) {
    const int buf = kt & 1;
    if (kt < 3) FC_STAGE(buf ^ 1, kt + 1);
    bf16x8 af[2][2], bfr[2][4];
#pragma unroll
    for (int kk = 0; kk < 2; ++kk) {
#pragma unroll
      for (int mi = 0; mi < 2; ++mi)
        af[kk][mi] =
            *(const bf16x8*)&As[buf * 4096 + (wm * 32 + mi * 16 + c) * 64 + kk * 32 + g * 8];
#pragma unroll
      for (int nj = 0; nj < 4; ++nj)
        bfr[kk][nj] =
            *(const bf16x8*)&Bsh[buf * 16384 + (wn * 64 + nj * 16 + c) * 64 + kk * 32 + g * 8];
    }
#pragma unroll
    for (int kk = 0; kk < 2; ++kk)
#pragma unroll
      for (int mi = 0; mi < 2; ++mi)
#pragma unroll
        for (int nj = 0; nj < 4; ++nj)
          acc[mi][nj] = __builtin_amdgcn_mfma_f32_16x16x32_bf16(af[kk][mi], bfr[kk][nj],
                                                                acc[mi][nj], 0, 0, 0);
    __syncthreads();
  }
#undef FC_STAGE

  // bias + residual (fp32) + per-row partial sums
#pragma unroll
  for (int mi = 0; mi < 2; ++mi)
#pragma unroll
    for (int r = 0; r < 4; ++r) {
      const int row = wm * 32 + mi * 16 + g * 4 + r;
      const int m = m0 + row;
      float s_ = 0.f, q_ = 0.f;
#pragma unroll
      for (int nj = 0; nj < 4; ++nj) {
        const int d = wn * 64 + nj * 16 + c;
        const float v = acc[mi][nj][r] + fcb[d] + x[(size_t)m * DIN + d];
        acc[mi][nj][r] = v;
        s_ += v;
        q_ += v * v;
      }
      red_s[row * 68 + wn * 16 + c] = s_;
      red_q[row * 68 + wn * 16 + c] = q_;
    }
  __syncthreads();
  if (tid < 64) {
    float ss = 0.f, qs = 0.f;
#pragma unroll 8
    for (int j = 0; j < 64; ++j) { ss += red_s[tid * 68 + j]; qs += red_q[tid * 68 + j]; }
    const float mu = ss * (1.f / DIN);
    const float var = qs * (1.f / DIN) - mu * mu;
    mu_l[tid] = mu;
    rs_l[tid] = rsqrtf(var + 1e-5f);
  }
  __syncthreads();
#pragma unroll
  for (int mi = 0; mi < 2; ++mi)
#pragma unroll
    for (int r = 0; r < 4; ++r) {
      const int row = wm * 32 + mi * 16 + g * 4 + r;
      const int m = m0 + row;
      const float mu = mu_l[row], rs = rs_l[row];
#pragma unroll
      for (int nj = 0; nj < 4; ++nj) {
        const int d = wn * 64 + nj * 16 + c;
        out[(size_t)m * DIN + d] = (acc[mi][nj][r] - mu) * rs * gamma[d] + beta[d];
      }
    }
}

// ---------------------------------------------------------------------------
extern "C" void kernel_launch(void* const* d_in, const int* in_sizes, int n_in,
                              void* d_out, int out_size, void* d_ws, size_t ws_size,
                              hipStream_t stream) {
  const float* x   = (const float*)d_in[0];
  const float* z   = (const float*)d_in[1];
  const float* wq  = (const float*)d_in[2];
  const float* bq  = (const float*)d_in[3];
  const float* fcw = (const float*)d_in[4];
  const float* fcb = (const float*)d_in[5];
  const float* g   = (const float*)d_in[6];
  const float* be  = (const float*)d_in[7];
  float* outp = (float*)d_out;

  unsigned short* q_bf  = (unsigned short*)d_ws;            // 8 MB
  unsigned short* z_bf  = q_bf + (size_t)NP * SEG * DQ;     // 8 MB
  unsigned short* x_bf  = z_bf + (size_t)NP * SEG * DQ;     // 8 MB (reused as att2)
  unsigned short* att2  = x_bf;                             // alias: qproj done w/ x_bf
  unsigned short* wq_bf = x_bf + (size_t)NP * SEG * DQ;     // 128 KB
  unsigned short* fw_bf = wq_bf + (size_t)DIN * NH * DQ;    // 128 KB

  k_cvt   <<<2080, 256, 0, stream>>>(z, x, wq, fcw, z_bf, x_bf, wq_bf, fw_bf);
  k_qproj2<<<512, 256, 0, stream>>>(x_bf, wq_bf, bq, q_bf);
  k_attn5 <<<NP * 2, 512, 0, stream>>>(q_bf, z_bf, att2);
  k_fcln2 <<<256, 512, 0, stream>>>(att2, fw_bf, x, fcb, g, be, outp);
}